// Round 17
// baseline (84.850 us; speedup 1.0000x reference)
//
#include <hip/hip_runtime.h>

#define HW    128
#define COUT  128
#define HSTR  144            // bytes per histogram row (16B aligned, bank-rotating)
#define H3SL  (16 * HSTR)    // 2304 B per H3 ring slot (16 out px)

// Per-block (= per-wave) LDS layout, 10080 B -> 16 blocks/CU (161 KB):
//   [0, 2592)         RAW: one 18-px histogram row (u8 bins, zeroed per row)
//   [2592, 9504)      H3[3] ring: horizontal-3-summed rows, 16 px x 144 B
//   [9504, 9824)      SxR int[4][20]: per-row per-padded-px (pc<<20)|ps
//   [9824, 10080)     SxH int[4][16]: horizontal-3 sums of SxR
#define RAW_OFF   0
#define H3_OFF    2592
#define SXR_OFF   9504
#define SXH_OFF   9824
#define LDS_BYTES 10080

typedef int v4i __attribute__((ext_vector_type(4)));

__device__ __forceinline__ int quad_sum(int v) {
  v += __builtin_amdgcn_mov_dpp(v, 0xB1, 0xF, 0xF, true);   // quad_perm xor1
  v += __builtin_amdgcn_mov_dpp(v, 0x4E, 0xF, 0xF, true);   // quad_perm xor2
  return v;
}
__device__ __forceinline__ int row16_sum(int v) {
  v = quad_sum(v);
  v += __builtin_amdgcn_mov_dpp(v, 0x114, 0xF, 0xF, true);  // row_shr:4
  v += __builtin_amdgcn_mov_dpp(v, 0x118, 0xF, 0xF, true);  // row_shr:8
  return v;                                                 // lane 15 of each 16-row: total
}

// ---------------------------------------------------------------------------
// Kernel 1: W_tab[o] = sum of quantized weights; Kt_g[o][v] i8 = K[v][o]-128
// where K[v][o] = #{w in o : qw*(128+v) > 32767}, v=0..127.
// ---------------------------------------------------------------------------
__global__ __launch_bounds__(512)
void build_tables(const float* __restrict__ weight, int* __restrict__ W_tab,
                  char* __restrict__ Kt_g) {
  __shared__ int qw_s[576];
  __shared__ int red_s[144];
  const int o = blockIdx.x;
  const int t = threadIdx.x;
  for (int j = t; j < 576; j += 512) {
    float w = weight[o * 576 + j];
    int q = (int)rintf(w * 255.f);
    qw_s[j] = q < 0 ? 0 : (q > 255 ? 255 : q);
  }
  __syncthreads();
  const int v = t >> 2, part = t & 3;
  const int i = 128 + v;                     // v==0 -> cnt=0 (qw*128<=32640)
  int cnt = 0;
  const int j0 = part * 144;
  for (int j = j0; j < j0 + 144; ++j) cnt += (qw_s[j] * i) > 32767 ? 1 : 0;
  cnt = quad_sum(cnt);
  if (part == 0) Kt_g[o * 128 + v] = (char)(cnt - 128);
  if (t < 144)
    red_s[t] = qw_s[t * 4] + qw_s[t * 4 + 1] + qw_s[t * 4 + 2] + qw_s[t * 4 + 3];
  __syncthreads();
  if (t == 0) {
    int s = 0;
    for (int kk = 0; kk < 144; ++kk) s += red_s[kk];
    W_tab[o] = s;
  }
}

// ---------------------------------------------------------------------------
// Kernel 2: ONE WAVE PER BLOCK, ZERO BARRIERS. Each wave owns a 16x2 output
// tile of one batch, with private LDS. Per input row (4 rows): quantize ->
// raw histogram (LDS atomics, wave-private) -> horizontal-3-sum into H3 ring
// (u8-exact) -> zero raw. At r>=2: i8 MFMA, K=384 = 3 stacked H3 rows
// (vertical window), accumulator = final 9-window K-sum -> in-register emit.
// B-fragments/W/bias read from global (L2-hot); B held 32 VGPR (k64-half).
// grid = 4096 blocks x 64 thr: 16 independent self-paced waves/CU.
// XCD locality: b = bid&7 (one batch per XCD; same-row w-tiles co-XCD).
// ---------------------------------------------------------------------------
__global__ __launch_bounds__(64, 4)
void pcilt_main(const float* __restrict__ x, const float* __restrict__ bias,
                const int* __restrict__ W_tab, const char* __restrict__ Kt_g,
                float* __restrict__ out) {
  __shared__ uint4 ldsv[LDS_BYTES / 16];
  char* ldsb = (char*)ldsv;
  unsigned char* RAW = (unsigned char*)(ldsb + RAW_OFF);
  unsigned char* H3B = (unsigned char*)(ldsb + H3_OFF);
  int* SxR = (int*)(ldsb + SXR_OFF);               // [4][20]
  int* SxH = (int*)(ldsb + SXH_OFF);               // [4][16]

  const int t   = (int)threadIdx.x;                // 0..63
  const int bid = (int)blockIdx.x;
  const int b   = bid & 7;                         // XCD owns one batch
  const int rem = bid >> 3;                        // 0..511
  const int h0  = (rem >> 3) * 2;                  // 64 h-strips of 2 rows
  const int w0  = (rem & 7) * 16;                  // 8 w-tiles of 16 px

  const int g  = t >> 4;                           // 0..3 (px group / kq)
  const int q  = t & 15;                           // ch-quad / o-sub / px-row

  const uint4 z4 = make_uint4(0, 0, 0, 0);
  // zero RAW (162 uint4)
#pragma unroll
  for (int p = 0; p < 3; ++p) {
    const int i = p * 64 + t;
    if (i < 162) ((uint4*)RAW)[i] = z4;
  }

  // W/bias per o-tile (o = nt*16 + q)
  float Wf[8], Bf[8];
#pragma unroll
  for (int nt = 0; nt < 8; ++nt) {
    Wf[nt] = (float)W_tab[nt * 16 + q];
    Bf[nt] = bias[nt * 16 + q];
  }
  // B-fragments, k64-half 0 (bins 0..63): lane q -> o row, g -> 16B k-chunk
  v4i Bfr[8];
#pragma unroll
  for (int nt = 0; nt < 8; ++nt)
    Bfr[nt] = *(const v4i*)(Kt_g + (nt * 16 + q) * 128 + g * 16);

  const size_t cs16k = (size_t)HW * HW;            // plane stride in floats

#pragma unroll
  for (int r = 0; r < 4; ++r) {
    const int iy  = h0 + r - 1;
    const int iyc = iy < 0 ? 0 : (iy > 127 ? 127 : iy);
    const bool rok = (iy >= 0) && (iy < HW);
    // ---- hist + Sx: 5 passes over 18 padded px (4 px-groups/pass) --------
#pragma unroll
    for (int p = 0; p < 5; ++p) {
      const int px = p * 4 + g;
      const bool pv = px < 18;
      const int ix = w0 + px - 1;
      const int ixc = ix < 0 ? 0 : (ix > 127 ? 127 : ix);
      const bool ok = pv && rok && (ix >= 0) && (ix < HW);
      const float* xp = x + ((size_t)b * 64 + q * 4) * cs16k + (size_t)iyc * HW + ixc;
      float f0 = xp[0], f1 = xp[cs16k], f2 = xp[2 * cs16k], f3 = xp[3 * cs16k];
      f0 = ok ? f0 : 0.f; f1 = ok ? f1 : 0.f; f2 = ok ? f2 : 0.f; f3 = ok ? f3 : 0.f;
      int q0 = (int)rintf(f0 * 255.f); q0 = q0 < 0 ? 0 : (q0 > 255 ? 255 : q0);
      int q1 = (int)rintf(f1 * 255.f); q1 = q1 < 0 ? 0 : (q1 > 255 ? 255 : q1);
      int q2 = (int)rintf(f2 * 255.f); q2 = q2 < 0 ? 0 : (q2 > 255 ? 255 : q2);
      int q3 = (int)rintf(f3 * 255.f); q3 = q3 < 0 ? 0 : (q3 > 255 ? 255 : q3);
      if (pv) {
        unsigned char* hp = RAW + px * HSTR;
        if (q0 > 128) { int v = q0 - 128; atomicAdd((unsigned*)(hp + ((v >> 2) << 2)), 1u << ((v & 3) * 8)); }
        if (q1 > 128) { int v = q1 - 128; atomicAdd((unsigned*)(hp + ((v >> 2) << 2)), 1u << ((v & 3) * 8)); }
        if (q2 > 128) { int v = q2 - 128; atomicAdd((unsigned*)(hp + ((v >> 2) << 2)), 1u << ((v & 3) * 8)); }
        if (q3 > 128) { int v = q3 - 128; atomicAdd((unsigned*)(hp + ((v >> 2) << 2)), 1u << ((v & 3) * 8)); }
      }
      int pk = (((q0 > 128) + (q1 > 128) + (q2 > 128) + (q3 > 128)) << 20) +
               (q0 + q1 + q2 + q3);
      pk = row16_sum(pk);
      if (pv && q == 15) SxR[r * 20 + px] = pk;
    }
    asm volatile("s_waitcnt lgkmcnt(0)" ::: "memory");
    // ---- H3[r%3]: horizontal 3-sum (u8-exact, 2 passes of b128) ----------
#pragma unroll
    for (int pp = 0; pp < 2; ++pp) {
      const int task = pp * 64 + t;                // 128 tasks: 16 px x 8 chunks
      const int px = task >> 3, ch = (task & 7) * 16;
      const unsigned char* rp = RAW + px * HSTR + ch;
      const uint4 a0 = *(const uint4*)rp;
      const uint4 a1 = *(const uint4*)(rp + HSTR);
      const uint4 a2 = *(const uint4*)(rp + 2 * HSTR);
      uint4 s;
      s.x = a0.x + a1.x + a2.x; s.y = a0.y + a1.y + a2.y;
      s.z = a0.z + a1.z + a2.z; s.w = a0.w + a1.w + a2.w;
      *(uint4*)(H3B + (r % 3) * H3SL + px * HSTR + ch) = s;
    }
    // ---- SxH[r]: horizontal 3-sum of SxR (lanes 0..15) -------------------
    if (t < 16) {
      SxH[r * 16 + t] = SxR[r * 20 + t] + SxR[r * 20 + t + 1] + SxR[r * 20 + t + 2];
    }
    // ---- zero RAW for next row (ordered after H3 reads by aliasing) ------
    if (r < 3) {
#pragma unroll
      for (int p = 0; p < 3; ++p) {
        const int i = p * 64 + t;
        if (i < 162) ((uint4*)RAW)[i] = z4;
      }
    }
    // ---- MFMA + emit out-row j = r-2 -------------------------------------
    if (r >= 2) {
      const int j = r - 2;
      asm volatile("s_waitcnt lgkmcnt(0)" ::: "memory");
      v4i acc[8];
#pragma unroll
      for (int nt = 0; nt < 8; ++nt) acc[nt] = (v4i){0, 0, 0, 0};
      // k64-half 0 (B already resident)
#pragma unroll
      for (int st = 0; st < 3; ++st) {
        const v4i a = *(const v4i*)(H3B + ((j + st) % 3) * H3SL + q * HSTR + g * 16);
#pragma unroll
        for (int nt = 0; nt < 8; ++nt)
          acc[nt] = __builtin_amdgcn_mfma_i32_16x16x64_i8(a, Bfr[nt], acc[nt], 0, 0, 0);
      }
      // k64-half 1 (bins 64..127)
#pragma unroll
      for (int nt = 0; nt < 8; ++nt)
        Bfr[nt] = *(const v4i*)(Kt_g + (nt * 16 + q) * 128 + 64 + g * 16);
#pragma unroll
      for (int st = 0; st < 3; ++st) {
        const v4i a = *(const v4i*)(H3B + ((j + st) % 3) * H3SL + q * HSTR + 64 + g * 16);
#pragma unroll
        for (int nt = 0; nt < 8; ++nt)
          acc[nt] = __builtin_amdgcn_mfma_i32_16x16x64_i8(a, Bfr[nt], acc[nt], 0, 0, 0);
      }
      // restore k64-half 0 for the next out-row
      if (j == 0) {
#pragma unroll
        for (int nt = 0; nt < 8; ++nt)
          Bfr[nt] = *(const v4i*)(Kt_g + (nt * 16 + q) * 128 + g * 16);
      }
      // Sx9 for this lane's 4 px (px = g*4 + rg)
      v4i s9 = (v4i){0, 0, 0, 0};
#pragma unroll
      for (int dy = 0; dy < 3; ++dy) {
        const v4i sv = *(const v4i*)&SxH[(j + dy) * 16 + g * 4];
        s9[0] += sv[0]; s9[1] += sv[1]; s9[2] += sv[2]; s9[3] += sv[3];
      }
      const int h = h0 + j;
#pragma unroll
      for (int nt = 0; nt < 8; ++nt) {
        const int o = nt * 16 + q;
        float4 u;
#pragma unroll
        for (int rg = 0; rg < 4; ++rg) {
          const int sx = s9[rg] & 0xFFFFF;
          const int sh = s9[rg] >> 20;
          ((float*)&u)[rg] = (float)sx * Wf[nt] -
                             65536.f * (float)(acc[nt][rg] + (sh << 7)) + Bf[nt];
        }
        *(float4*)(out + ((size_t)(b * COUT + o) * HW + h) * HW + w0 + g * 4) = u;
      }
    }
  }
}

// ---------------------------------------------------------------------------
extern "C" void kernel_launch(void* const* d_in, const int* in_sizes, int n_in,
                              void* d_out, int out_size, void* d_ws, size_t ws_size,
                              hipStream_t stream) {
  const float* x      = (const float*)d_in[0];
  const float* weight = (const float*)d_in[1];
  const float* bias   = (const float*)d_in[2];
  float* out = (float*)d_out;

  int*  W_tab = (int*)d_ws;
  char* Kt_g  = (char*)d_ws + 512;

  build_tables<<<128, 512, 0, stream>>>(weight, W_tab, Kt_g);

  pcilt_main<<<4096, 64, 0, stream>>>(x, bias, W_tab, Kt_g, out);
}

// Round 18
// 41.267 us; speedup vs baseline: 2.0561x; 2.0561x over previous
//
#include <hip/hip_runtime.h>

#define CIN   64
#define HW    128
#define COUT  128
#define TH    8
#define TW    32
#define PXR   34
#define NITER (TH + 2)      // 10 iterations (R11 two-barrier structure)
#define NTHR  512
#define HSTR  144           // bytes per histogram row (16B aligned)
#define AKSTR 136           // u16 per AK row -> 272 B (16B aligned)
#define SLOT  (PXR * HSTR)  // 4896 B per H ring slot

// LDS layout (bytes):
//   [0, 19584)        Hm[4] ring slots, 34 rows x 144 B
//   [19584, 35968)    Kt i8[128][128] (prologue) / AK u16[48][136] (loop)
//   [35968, 36608)    Sx int[4][40] reduced (pc<<20)|ps per pixel
//   [36608, 39872)    Sxp int[2][34][12] quad-partials (segs 0..3 + pad)
#define HM_OFF    0
#define KT_OFF    19584
#define SX_OFF    35968
#define SXP_OFF   36608
#define LDS_BYTES 39872

typedef int v4i __attribute__((ext_vector_type(4)));

// lgkm-only barrier: drains LDS ops, leaves global loads/stores in flight.
__device__ __forceinline__ void wg_barrier() {
  asm volatile("s_waitcnt lgkmcnt(0)\n\ts_barrier" ::: "memory");
}

// sum over each aligned 4-lane quad via DPP (VALU pipe, no LDS traffic).
__device__ __forceinline__ int quad_sum(int v) {
  v += __builtin_amdgcn_mov_dpp(v, 0xB1, 0xF, 0xF, true);
  v += __builtin_amdgcn_mov_dpp(v, 0x4E, 0xF, 0xF, true);
  return v;
}

// ---------------------------------------------------------------------------
// Kernel 1: W_tab[o] = sum of quantized weights; Kt_g[o][v] i8 = K[v][o]-128
// where K[v][o] = #{w in o : qw*(128+v) > 32767}, v=0..127 (K<=255, ~7 sigma).
// ---------------------------------------------------------------------------
__global__ __launch_bounds__(512)
void build_tables(const float* __restrict__ weight, int* __restrict__ W_tab,
                  char* __restrict__ Kt_g) {
  __shared__ int qw_s[576];
  __shared__ int red_s[144];
  const int o = blockIdx.x;
  const int t = threadIdx.x;
  for (int j = t; j < 576; j += 512) {
    float w = weight[o * 576 + j];
    int q = (int)rintf(w * 255.f);
    qw_s[j] = q < 0 ? 0 : (q > 255 ? 255 : q);
  }
  __syncthreads();
  const int v = t >> 2, part = t & 3;
  const int i = 128 + v;                     // v==0 -> cnt=0 (qw*128<=32640)
  int cnt = 0;
  const int j0 = part * 144;
  for (int j = j0; j < j0 + 144; ++j) cnt += (qw_s[j] * i) > 32767 ? 1 : 0;
  cnt = quad_sum(cnt);
  if (part == 0) Kt_g[o * 128 + v] = (char)(cnt - 128);
  if (t < 144)
    red_s[t] = qw_s[t * 4] + qw_s[t * 4 + 1] + qw_s[t * 4 + 2] + qw_s[t * 4 + 3];
  __syncthreads();
  if (t == 0) {
    int s = 0;
    for (int kk = 0; kk < 144; ++kk) s += red_s[kk];
    W_tab[o] = s;
  }
}

// ---------------------------------------------------------------------------
// Kernel 2: identical to the 41.2 us R11 kernel EXCEPT the 8 output stores
// are nontemporal (output is write-once-never-read; keep L2 for x reuse).
// ---------------------------------------------------------------------------
__global__ __launch_bounds__(NTHR, 4)
void pcilt_main(const float* __restrict__ x, const float* __restrict__ bias,
                const int* __restrict__ W_tab, const char* __restrict__ Kt_g,
                float* __restrict__ out) {
  __shared__ uint4 ldsv[LDS_BYTES / 16];
  char* ldsb = (char*)ldsv;
  unsigned char* HmB  = (unsigned char*)(ldsb + HM_OFF);
  unsigned char* KtB  = (unsigned char*)(ldsb + KT_OFF);
  unsigned short* AK  = (unsigned short*)(ldsb + KT_OFF);
  int* Sx             = (int*)(ldsb + SX_OFF);     // [4][40], entries 0..33 used
  int* Sxp            = (int*)(ldsb + SXP_OFF);    // [2][34][12]

  const int t   = (int)threadIdx.x;
  const int bid = (int)blockIdx.x;
  const int b  = bid & 7;                          // XCD owns one batch
  const int k  = bid >> 3;
  const int h0 = (k >> 2) * TH;
  const int w0 = (k & 3) * TW;

  for (int i = t; i < 4096; i += NTHR)
    ((unsigned int*)KtB)[i] = ((const unsigned int*)Kt_g)[i];
  {
    const uint4 z4 = make_uint4(0, 0, 0, 0);
    for (int i = t; i < 4 * SLOT / 16; i += NTHR) ((uint4*)HmB)[i] = z4;
  }

  const int l    = t & 15;
  const int slot = t >> 4;
  const int w    = t >> 6;
  const int kq   = (t >> 4) & 3;
  const int we   = t & 31;
  const int og   = t >> 5;

  float wf[8], bi[8];
#pragma unroll
  for (int m = 0; m < 8; ++m) {
    wf[m] = (float)W_tab[og * 8 + m];
    bi[m] = bias[og * 8 + m];
  }

  wg_barrier();

  // hoist B-fragments (Kt LDS is dead afterwards; AK reuses its space)
  v4i bfr[4][2];
  const int Mt = w >> 1, Nh = w & 1;
  if (w < 6) {
#pragma unroll
    for (int nt = 0; nt < 4; ++nt)
#pragma unroll
      for (int k64 = 0; k64 < 2; ++k64)
        bfr[nt][k64] = *(const v4i*)(KtB + (Nh * 64 + nt * 16 + l) * 128 +
                                     k64 * 64 + kq * 16);
  }

  float pf0[4], pf1[4];
  const float* xb = x + ((size_t)b * CIN + l * 4) * (HW * HW);
  const size_t cs = (size_t)HW * HW;

#define ISSUE(rn)                                                              \
  {                                                                            \
    const int iy  = h0 + (rn)-1;                                               \
    const int iyc = iy < 0 ? 0 : (iy > 127 ? 127 : iy);                        \
    const bool rok = (iy >= 0) && (iy < HW);                                   \
    int ix = w0 + slot - 1;                                                    \
    int ixc = ix < 0 ? 0 : (ix > 127 ? 127 : ix);                              \
    bool ok = rok && (ix >= 0) && (ix < HW);                                   \
    const float* xp = xb + (size_t)iyc * HW + ixc;                             \
    float v0 = xp[0], v1 = xp[cs], v2 = xp[2 * cs], v3 = xp[3 * cs];           \
    pf0[0] = ok ? v0 : 0.f; pf0[1] = ok ? v1 : 0.f;                            \
    pf0[2] = ok ? v2 : 0.f; pf0[3] = ok ? v3 : 0.f;                            \
    if (slot < 2) {                                                            \
      ix = w0 + 32 + slot - 1;                                                 \
      ixc = ix > 127 ? 127 : ix;                                               \
      ok = rok && (ix < HW);                                                   \
      const float* xq = xb + (size_t)iyc * HW + ixc;                           \
      float u0 = xq[0], u1 = xq[cs], u2 = xq[2 * cs], u3 = xq[3 * cs];         \
      pf1[0] = ok ? u0 : 0.f; pf1[1] = ok ? u1 : 0.f;                          \
      pf1[2] = ok ? u2 : 0.f; pf1[3] = ok ? u3 : 0.f;                          \
    }                                                                          \
  }

// Sx: quad_sum (VALU) -> 4 partials/pixel, scatter-written conflict-free.
#define STAGEPX(pf, px)                                                        \
  {                                                                            \
    int q, iv0, iv1, iv2, iv3;                                                 \
    q = (int)rintf((pf)[0] * 255.f); iv0 = q < 0 ? 0 : (q > 255 ? 255 : q);    \
    q = (int)rintf((pf)[1] * 255.f); iv1 = q < 0 ? 0 : (q > 255 ? 255 : q);    \
    q = (int)rintf((pf)[2] * 255.f); iv2 = q < 0 ? 0 : (q > 255 ? 255 : q);    \
    q = (int)rintf((pf)[3] * 255.f); iv3 = q < 0 ? 0 : (q > 255 ? 255 : q);    \
    int pk = (((iv0 > 128) + (iv1 > 128) + (iv2 > 128) + (iv3 > 128)) << 20) + \
             (iv0 + iv1 + iv2 + iv3);                                          \
    pk = quad_sum(pk);                                                         \
    if ((l & 3) == 0) Sxp[sxpb + (px)*12 + (l >> 2)] = pk;                     \
    unsigned char* hp = Hc + (px)*HSTR;                                        \
    if (iv0 > 128) { int v = iv0 - 128; atomicAdd((unsigned int*)(hp + ((v >> 2) << 2)), 1u << ((v & 3) * 8)); } \
    if (iv1 > 128) { int v = iv1 - 128; atomicAdd((unsigned int*)(hp + ((v >> 2) << 2)), 1u << ((v & 3) * 8)); } \
    if (iv2 > 128) { int v = iv2 - 128; atomicAdd((unsigned int*)(hp + ((v >> 2) << 2)), 1u << ((v & 3) * 8)); } \
    if (iv3 > 128) { int v = iv3 - 128; atomicAdd((unsigned int*)(hp + ((v >> 2) << 2)), 1u << ((v & 3) * 8)); } \
  }

  ISSUE(0);

  for (int r = 0; r < NITER; ++r) {
    // ---------------- stage row r from prefetched regs; issue row r+1 ------
    {
      unsigned char* Hc = HmB + (r & 3) * SLOT;
      const int sxpb = (r & 1) * (34 * 12);
      STAGEPX(pf0, slot);
      if (slot < 2) STAGEPX(pf1, 32 + slot);
      if (r + 1 < NITER) ISSUE(r + 1);
    }
    wg_barrier();

    // ---------------- phase 2: MFMA (0-5) / Sx-tree (6) / zero (7) ---------
    if (r >= 2 && w < 6) {
      v4i acc[4];
#pragma unroll
      for (int nt = 0; nt < 4; ++nt) acc[nt] = (v4i){0, 0, 0, 0};
      const int prow = Mt * 16 + l;              // rows >=34 overflow into
#pragma unroll                                   // Kt/AK region: garbage D
      for (int st = 0; st < 3; ++st) {           // rows 34..47, never emitted
        const unsigned char* Hs = HmB + ((r - 2 + st) & 3) * SLOT +
                                  prow * HSTR + kq * 16;
#pragma unroll
        for (int k64 = 0; k64 < 2; ++k64) {
          const v4i a = *(const v4i*)(Hs + k64 * 64);
#pragma unroll
          for (int nt = 0; nt < 4; ++nt)
            acc[nt] = __builtin_amdgcn_mfma_i32_16x16x64_i8(a, bfr[nt][k64], acc[nt], 0, 0, 0);
        }
      }
      const int pbase = Mt * 16 + kq * 4;
#pragma unroll
      for (int nt = 0; nt < 4; ++nt) {
        const int o = Nh * 64 + nt * 16 + l;
#pragma unroll
        for (int rg = 0; rg < 4; ++rg)
          AK[(pbase + rg) * AKSTR + o] = (unsigned short)acc[nt][rg];
      }
    }
    if (w == 6) {                                // finish Sx: 4 segs -> 1
      const int L = t - 384;
      if (L < 34) {
        const v4i sq = *(const v4i*)&Sxp[(r & 1) * (34 * 12) + L * 12];
        Sx[(r & 3) * 40 + L] = sq.x + sq.y + sq.z + sq.w;
      }
    }
    if (w == 7) {                                // zero H slot r+1
      uint4* Hn = (uint4*)(HmB + ((r + 1) & 3) * SLOT);
      const uint4 z4 = make_uint4(0, 0, 0, 0);
      for (int i2 = t - 448; i2 < SLOT / 16; i2 += 64) Hn[i2] = z4;
    }
    wg_barrier();

    // ---------------- emit out-row h0 + r - 2 (nontemporal stores) ---------
    if (r >= 2) {
      const int h = h0 + r - 2;
      int v9 = 0;
#pragma unroll
      for (int q = 0; q < 3; ++q) {
        const int sl = (r - 2 + q) & 3;
        v9 += Sx[sl * 40 + we] + Sx[sl * 40 + we + 1] + Sx[sl * 40 + we + 2];
      }
      const int sx9 = v9 & 0xFFFFF;
      const int sh9 = v9 >> 20;
      int k0 = 0, k1 = 0, k2 = 0, k3 = 0, k4 = 0, k5 = 0, k6 = 0, k7 = 0;
#pragma unroll
      for (int dx = 0; dx < 3; ++dx) {
        const uint4 p = *(const uint4*)&AK[(we + dx) * AKSTR + og * 8];
        k0 += (int)(short)(p.x & 0xffffu); k1 += (int)(short)(p.x >> 16);
        k2 += (int)(short)(p.y & 0xffffu); k3 += (int)(short)(p.y >> 16);
        k4 += (int)(short)(p.z & 0xffffu); k5 += (int)(short)(p.z >> 16);
        k6 += (int)(short)(p.w & 0xffffu); k7 += (int)(short)(p.w >> 16);
      }
      const int kc = 128 * sh9;
      const float sxf = (float)sx9;
      float* op = out + (((size_t)b * COUT + og * 8) * HW + h) * HW + (w0 + we);
      const size_t os = (size_t)HW * HW;
      __builtin_nontemporal_store(sxf * wf[0] - 65536.f * (float)(k0 + kc) + bi[0], op + 0 * os);
      __builtin_nontemporal_store(sxf * wf[1] - 65536.f * (float)(k1 + kc) + bi[1], op + 1 * os);
      __builtin_nontemporal_store(sxf * wf[2] - 65536.f * (float)(k2 + kc) + bi[2], op + 2 * os);
      __builtin_nontemporal_store(sxf * wf[3] - 65536.f * (float)(k3 + kc) + bi[3], op + 3 * os);
      __builtin_nontemporal_store(sxf * wf[4] - 65536.f * (float)(k4 + kc) + bi[4], op + 4 * os);
      __builtin_nontemporal_store(sxf * wf[5] - 65536.f * (float)(k5 + kc) + bi[5], op + 5 * os);
      __builtin_nontemporal_store(sxf * wf[6] - 65536.f * (float)(k6 + kc) + bi[6], op + 6 * os);
      __builtin_nontemporal_store(sxf * wf[7] - 65536.f * (float)(k7 + kc) + bi[7], op + 7 * os);
    }
  }
}

// ---------------------------------------------------------------------------
extern "C" void kernel_launch(void* const* d_in, const int* in_sizes, int n_in,
                              void* d_out, int out_size, void* d_ws, size_t ws_size,
                              hipStream_t stream) {
  const float* x      = (const float*)d_in[0];
  const float* weight = (const float*)d_in[1];
  const float* bias   = (const float*)d_in[2];
  float* out = (float*)d_out;

  int*  W_tab = (int*)d_ws;
  char* Kt_g  = (char*)d_ws + 512;

  build_tables<<<128, 512, 0, stream>>>(weight, W_tab, Kt_g);

  pcilt_main<<<512, NTHR, 0, stream>>>(x, bias, W_tab, Kt_g, out);
}